// Round 9
// baseline (153.689 us; speedup 1.0000x reference)
//
#include <hip/hip_runtime.h>

// SlidingWindowAttention: B=1, S=4096, D=1024, H=16, d=64, WIN=512 (256 back / 255 fwd)
// Inputs/outputs FP32 storage (values bf16-rounded by harness).
//
// Pipeline (4 dispatches):
//   0) cvt_all   : x|Wqkv|Wout -> bf16 (contiguous ws) + zero Kp/VTp pad tiles
//   1) gemm_qkv  : 128x128 tile (m97 structure), BK=64, grid (24,32)=768 = 3/CU
//   2) swa_fused : R20: 128 q/block, 8 waves (512 thr), grid 512 = 2 blocks/CU
//                  (16 waves/CU preserved). Two q-strips share K/V staging:
//                  10 x 64-key dbuf rounds per block (was 9 per 64-q block)
//                  -> per-q staging rounds halved. Strip s skips its
//                  out-of-band tile via uniform (u-s)<9 test.
//   3) gemm_out  : 64x64 tile @ 4 blocks/CU, XCD-contiguous remap,
//                  double-buffered LDS (one barrier/round)
//
// R19 NOTE: cooperative-launch dispatch fusion FAILED in this harness
// (graph-capture incompatible + cross-XCD o-handoff race). Do NOT re-attempt.

typedef __bf16 bf16x8 __attribute__((ext_vector_type(8)));
typedef float f32x4 __attribute__((ext_vector_type(4)));
typedef unsigned short u16;
typedef unsigned int u32;

#define MFMA16(a, b, c) __builtin_amdgcn_mfma_f32_16x16x32_bf16(a, b, c, 0, 0, 0)

__device__ __forceinline__ u16 f2b(float f) {   // RNE f32 -> bf16 bits
  union { float f; u32 u; } x; x.f = f;
  u32 r = x.u + 0x7fffu + ((x.u >> 16) & 1u);
  return (u16)(r >> 16);
}

union U8x16 { int4 v; u16 u[8]; };

// async 16B global -> LDS (dest = wave-uniform base + lane*16, HW-generated)
__device__ __forceinline__ void gll16(const u16* g, u16* l) {
  __builtin_amdgcn_global_load_lds(
      (const __attribute__((address_space(1))) u16*)g,
      (__attribute__((address_space(3))) u16*)l, 16, 0, 0);
}

// ---------------------------------------------------------------------------
// fp32 -> bf16 for all three inputs (chunks 0..1048575, contiguous dst) plus
// pad-zeroing of Kp (chunks +0..65535) and VTp (chunks +65536..131071).
// ---------------------------------------------------------------------------
__global__ void cvt_all(const float* __restrict__ x, const float* __restrict__ wqkv,
                        const float* __restrict__ wout, u16* __restrict__ dst,
                        u16* __restrict__ Kp, u16* __restrict__ VTp)
{
  const int i = blockIdx.x * blockDim.x + threadIdx.x;   // chunk index
  if (i < 1048576) {
    const float* src; int off;
    if (i < 524288)       { src = x;    off = i; }           // 4096*1024/8
    else if (i < 917504)  { src = wqkv; off = i - 524288; }  // +3072*1024/8
    else                  { src = wout; off = i - 917504; }  // +1024*1024/8
    const float4 a = ((const float4*)src)[off * 2];
    const float4 b = ((const float4*)src)[off * 2 + 1];
    U8x16 t;
    t.u[0] = f2b(a.x); t.u[1] = f2b(a.y); t.u[2] = f2b(a.z); t.u[3] = f2b(a.w);
    t.u[4] = f2b(b.x); t.u[5] = f2b(b.y); t.u[6] = f2b(b.z); t.u[7] = f2b(b.w);
    ((int4*)dst)[i] = t.v;
    return;
  }
  const int j = i - 1048576;
  const int4 z = {0, 0, 0, 0};
  if (j < 65536) {        // Kp pad rows: per h, rows [0,256) and [4352,4608)
    const int h = j >> 12, rem = j & 4095;
    const int row512 = rem >> 3, c8 = (rem & 7) * 8;
    const int row = (row512 < 256) ? row512 : (4096 + row512);
    *(int4*)(&Kp[((long)h * 4608 + row) * 64 + c8]) = z;
  } else {                // VTp pad cols: per h, keys [0,256) and [4352,4608)
    const int j2 = j - 65536;
    const int h = j2 >> 12, rem = j2 & 4095;
    const int d = rem >> 6, kc = rem & 63;
    const int key = (kc < 32) ? kc * 8 : (4096 + kc * 8);
    *(int4*)(&VTp[((long)h * 64 + d) * 4608 + key]) = z;
  }
}

// ---------------------------------------------------------------------------
// QKV GEMM: 128x128 tile (m97 structure), BK=64, grid (24, 32) = 768 blocks
// = 3/CU. LDS 32 KB shared pool. 4 waves x 64x64 quadrant, 32 MFMA/round.
// Epilogue: Q -> Qb * 0.125; K -> Kp direct scatter; V -> 32KB LDS re-tile.
// ---------------------------------------------------------------------------
__global__ __launch_bounds__(256, 3) void gemm_qkv(
    const u16* __restrict__ A, const u16* __restrict__ B,
    const float* __restrict__ bias,
    u16* __restrict__ Qb, u16* __restrict__ Kp, u16* __restrict__ VTp)
{
  __shared__ u16 smem[16384];    // 32 KB: As = smem[0..8191], Bs = smem[8192..]
  u16* const As = smem;          // 128 x 64
  u16* const Bs = smem + 8192;   // 128 x 64

  const int K = 1024;
  const int tid  = threadIdx.x;
  const int lane = tid & 63;
  const int wave = tid >> 6;
  const int quad = lane >> 4;
  const int c16  = lane & 15;
  const int wr   = wave >> 1;            // M half (64 rows)
  const int wc   = wave & 1;             // N half (64 cols)
  const long m0 = (long)blockIdx.y * 128;
  const long n0 = (long)blockIdx.x * 128;

  const int rowo   = lane >> 3;
  const int schunk = (lane & 7) ^ rowo;
  const u16* gA0 = &A[(m0 + wave * 32 + rowo) * K + schunk * 8];
  const u16* gA1 = gA0 + 8 * K;
  const u16* gA2 = gA0 + 16 * K;
  const u16* gA3 = gA0 + 24 * K;
  const u16* gB0 = &B[(n0 + wave * 32 + rowo) * K + schunk * 8];
  const u16* gB1 = gB0 + 8 * K;
  const u16* gB2 = gB0 + 16 * K;
  const u16* gB3 = gB0 + 24 * K;
  u16* const lA0 = &As[(wave * 32) * 64];
  u16* const lA1 = lA0 + 8 * 64;
  u16* const lA2 = lA0 + 16 * 64;
  u16* const lA3 = lA0 + 24 * 64;
  u16* const lB0 = &Bs[(wave * 32) * 64];
  u16* const lB1 = lB0 + 8 * 64;
  u16* const lB2 = lB0 + 16 * 64;
  u16* const lB3 = lB0 + 24 * 64;

  const int rsw  = c16 & 7;
  const int off0 = (quad ^ rsw) * 8;
  const int off1 = ((4 + quad) ^ rsw) * 8;
  const u16* rA[4]; const u16* rB[4];
#pragma unroll
  for (int i = 0; i < 4; ++i) rA[i] = &As[(wr * 64 + i * 16 + c16) * 64];
#pragma unroll
  for (int j = 0; j < 4; ++j) rB[j] = &Bs[(wc * 64 + j * 16 + c16) * 64];

  f32x4 acc[4][4];
#pragma unroll
  for (int i = 0; i < 4; ++i)
#pragma unroll
    for (int j = 0; j < 4; ++j)
      acc[i][j] = f32x4{0.f, 0.f, 0.f, 0.f};

  for (int k0 = 0; k0 < K; k0 += 64) {
    __syncthreads();
    gll16(gA0, lA0); gll16(gA1, lA1); gll16(gA2, lA2); gll16(gA3, lA3);
    gll16(gB0, lB0); gll16(gB1, lB1); gll16(gB2, lB2); gll16(gB3, lB3);
    gA0 += 64; gA1 += 64; gA2 += 64; gA3 += 64;
    gB0 += 64; gB1 += 64; gB2 += 64; gB3 += 64;
    __syncthreads();

#pragma unroll
    for (int h = 0; h < 2; ++h) {
      const int off = h ? off1 : off0;
      bf16x8 af[4], bfr[4];
#pragma unroll
      for (int i = 0; i < 4; ++i) af[i]  = *(const bf16x8*)(rA[i] + off);
#pragma unroll
      for (int j = 0; j < 4; ++j) bfr[j] = *(const bf16x8*)(rB[j] + off);
#pragma unroll
      for (int i = 0; i < 4; ++i)
#pragma unroll
        for (int j = 0; j < 4; ++j)
          acc[i][j] = MFMA16(af[i], bfr[j], acc[i][j]);
    }
  }

  const int region = (int)(n0 >> 10);      // 0=Q, 1=K, 2=V (block-uniform)
  if (region == 2) {
    // V: re-tile through LDS (transposed, 16-slot swizzled), then coalesced
    // 16B stores: 16 consecutive lanes cover one (h,d) row's 128 keys = 256 B.
    __syncthreads();                        // fragment reads of smem complete
    u16* const Ts = smem;                   // 128 cols x 128 keys (32 KB)
#pragma unroll
    for (int i = 0; i < 4; ++i)
#pragma unroll
      for (int j = 0; j < 4; ++j) {
        const int col = wc * 64 + j * 16 + c16;
        const float bv = bias[n0 + col];
#pragma unroll
        for (int r = 0; r < 4; ++r) {
          const int key  = wr * 64 + i * 16 + quad * 4 + r;   // block-local
          const int slot = (key >> 3) ^ (col & 15);
          Ts[col * 128 + slot * 8 + (key & 7)] = f2b(acc[i][j][r] + bv);
        }
      }
    __syncthreads();
    const int base_n1 = (int)(n0 - 2048);
#pragma unroll
    for (int k = 0; k < 8; ++k) {
      const int idx  = k * 256 + tid;
      const int col  = idx >> 4, kc = idx & 15;
      const int slot = kc ^ (col & 15);
      const int4 v = *(const int4*)(&Ts[col * 128 + slot * 8]);
      const int n1 = base_n1 + col;
      const int h = n1 >> 6, d = n1 & 63;
      *(int4*)(&VTp[((long)h * 64 + d) * 4608 + 256 + m0 + kc * 8]) = v;
    }
    return;
  }

#pragma unroll
  for (int i = 0; i < 4; ++i) {
    const long row0 = m0 + wr * 64 + i * 16 + quad * 4;
#pragma unroll
    for (int j = 0; j < 4; ++j) {
      const long col = n0 + wc * 64 + j * 16 + c16;
      const float bv = bias[col];
      if (region == 0) {
        // fold the 1/sqrt(d)=0.125 score scale into Q (exact pow2 scaling)
#pragma unroll
        for (int r = 0; r < 4; ++r)
          Qb[(row0 + r) * 1024 + col] = f2b((acc[i][j][r] + bv) * 0.125f);
      } else {
        const int n1 = (int)(col - 1024);
        const int h = n1 >> 6, d = n1 & 63;
#pragma unroll
        for (int r = 0; r < 4; ++r)
          Kp[((long)h * 4608 + row0 + r + 256) * 64 + d] = f2b(acc[i][j][r] + bv);
      }
    }
  }
}

// ---------------------------------------------------------------------------
// Output GEMM: 64x64 tile, BK=64, flat grid 1024 = 4 blocks/CU.
// XCD-contiguous remap: lb = (b&7)*128 + (b>>3), bijective on 1024.
// Double-buffered LDS; one barrier/round. 8 MFMA/round, 16 rounds. fp32 out.
// ---------------------------------------------------------------------------
__global__ __launch_bounds__(256, 4) void gemm_out(
    const u16* __restrict__ A, const u16* __restrict__ B,
    const float* __restrict__ bias, float* __restrict__ C)
{
  __shared__ u16 As[2][64 * 64];   // 16 KB
  __shared__ u16 Bs[2][64 * 64];   // 16 KB

  const int K = 1024, N = 1024;
  const int tid  = threadIdx.x;
  const int lane = tid & 63;
  const int wave = tid >> 6;
  const int quad = lane >> 4;
  const int c16  = lane & 15;
  const int wr   = wave >> 1;
  const int wc   = wave & 1;
  const int b    = blockIdx.x;
  const int lb   = (b & 7) * 128 + (b >> 3);   // XCD-contiguous (bijective)
  const long m0 = (long)(lb >> 4) * 64;
  const long n0 = (long)(lb & 15) * 64;

  const int rowo   = lane >> 3;
  const int schunk = (lane & 7) ^ rowo;
  const u16* gA0 = &A[(m0 + wave * 16 + rowo) * K + schunk * 8];
  const u16* gA1 = gA0 + 8 * K;
  const u16* gB0 = &B[(n0 + wave * 16 + rowo) * K + schunk * 8];
  const u16* gB1 = gB0 + 8 * K;
  const int lso = (wave * 16) * 64;            // wave's staging offset in a buf

  const int rsw  = c16 & 7;
  const int off0 = (quad ^ rsw) * 8;
  const int off1 = ((4 + quad) ^ rsw) * 8;
  const int ra0 = (wr * 32 + c16) * 64;        // fragment row offsets in a buf
  const int ra1 = (wr * 32 + 16 + c16) * 64;
  const int rb0 = (wc * 32 + c16) * 64;
  const int rb1 = (wc * 32 + 16 + c16) * 64;

  f32x4 acc[2][2];
#pragma unroll
  for (int i = 0; i < 2; ++i)
#pragma unroll
    for (int j = 0; j < 2; ++j)
      acc[i][j] = f32x4{0.f, 0.f, 0.f, 0.f};

  auto stage = [&](u16* Ab, u16* Bb) {
    gll16(gA0, Ab + lso); gll16(gA1, Ab + lso + 512);
    gll16(gB0, Bb + lso); gll16(gB1, Bb + lso + 512);
    gA0 += 64; gA1 += 64; gB0 += 64; gB1 += 64;
  };

  auto compute = [&](const u16* Ab, const u16* Bb) {
#pragma unroll
    for (int h = 0; h < 2; ++h) {
      const int off = h ? off1 : off0;
      bf16x8 af[2], bfr[2];
      af[0]  = *(const bf16x8*)(Ab + ra0 + off);
      af[1]  = *(const bf16x8*)(Ab + ra1 + off);
      bfr[0] = *(const bf16x8*)(Bb + rb0 + off);
      bfr[1] = *(const bf16x8*)(Bb + rb1 + off);
#pragma unroll
      for (int i = 0; i < 2; ++i)
#pragma unroll
        for (int j = 0; j < 2; ++j)
          acc[i][j] = MFMA16(af[i], bfr[j], acc[i][j]);
    }
  };

  u16* const A0 = &As[0][0]; u16* const A1 = &As[1][0];
  u16* const B0 = &Bs[0][0]; u16* const B1 = &Bs[1][0];

  stage(A0, B0);                   // t0 -> buf0
  __syncthreads();
  for (int uu = 0; uu < 7; ++uu) { // rounds t=2uu, 2uu+1  (t=0..13)
    stage(A1, B1);                 // t+1 -> buf1
    compute(A0, B0);               // t
    __syncthreads();
    stage(A0, B0);                 // t+2 -> buf0
    compute(A1, B1);               // t+1
    __syncthreads();
  }
  stage(A1, B1);                   // t15 -> buf1
  compute(A0, B0);                 // t14
  __syncthreads();
  compute(A1, B1);                 // t15

#pragma unroll
  for (int i = 0; i < 2; ++i) {
    const long row0 = m0 + wr * 32 + i * 16 + quad * 4;
#pragma unroll
    for (int j = 0; j < 2; ++j) {
      const long col = n0 + wc * 32 + j * 16 + c16;
      const float bv = bias[col];
#pragma unroll
      for (int r = 0; r < 4; ++r)
        C[(row0 + r) * N + col] = acc[i][j][r] + bv;
    }
  }
}

// ---------------------------------------------------------------------------
// Sliding-window flash attention. R20: 128 q/block, 8 waves (512 threads),
// grid 512 = 2 blocks/CU (16 waves/CU, same as the 4-wave version).
// Wave v: strip s = v>>2 (q in [qb0 + s*64, +64)), w = v&3; handles 16 q rows
// qb0 + s*64 + w*16 + c16. Two strips SHARE the staged K/V tiles.
//
// 10 x 64-key double-buffered rounds cover padded keys [qb0, qb0+640)
// exactly (no OOB staging). Strip s computes round u iff (u32)(u-s) < 9
// (strip0 skips tile 9, strip1 skips tile 0 -- its keys are out-of-band).
// Staging per wave per tile: 1 K gll16 (key rows [v*8,+8)) + 1 V gll16
// (d rows [v*8,+8)), slot = chunk ^ (row&7), pre-swizzled global chunk.
// Swapped-QK^T softmax (S^T via MFMA16(bk,aq)): lane holds
// S[key = tcol*16 + quad*4 + r][q = c16]; P-store = 8 cvt_pk + 8 ds_write_b32;
// rsum scalar/lane + 2 shfl_xor; delta = dbase + u*64 + tcol*16 + r with
// dbase = quad*4 - s*64 - w*16 - c16.
// LDS: Ks dbuf 16K + Vs dbuf 16K + Ps 8 waves x 2K = 48 KB.
// ---------------------------------------------------------------------------
__global__ __launch_bounds__(512, 4) void swa_fused(
    const u16* __restrict__ Qb, const u16* __restrict__ Kp,
    const u16* __restrict__ VTp, u16* __restrict__ o)
{
  __shared__ u16 Ks[2][64 * 64];    // (key, d) dbuf   16 KB
  __shared__ u16 Vs[2][64 * 64];    // (d, key) dbuf   16 KB
  __shared__ u16 Ps[8 * 16 * 64];   // per-wave (q,key) 16 KB

  const int tid  = threadIdx.x;
  const int lane = tid & 63;
  const int v    = tid >> 6;            // wave 0..7
  const int s    = v >> 2;              // q-strip 0/1
  const int w    = v & 3;               // strip-local wave
  const int quad = lane >> 4;
  const int c16  = lane & 15;

  // XCD-locality remap: b -> (h, qb0); 512 blocks = 8 xcd x 2 heads x 32 qb
  const int b    = blockIdx.x;
  const int xcd  = b & 7;
  const int idx  = b >> 3;               // 0..63, ascending in launch order
  const int h    = xcd * 2 + (idx >> 5); // heads {2x, 2x+1}
  const int qb0  = (idx & 31) * 128;     // qb ascending within XCD

  const long qrow = qb0 + s * 64 + w * 16 + c16;
  const bf16x8 aq0 = *(const bf16x8*)(&Qb[qrow * 1024 + h * 64 + quad * 8]);
  const bf16x8 aq1 = *(const bf16x8*)(&Qb[qrow * 1024 + h * 64 + 32 + quad * 8]);

  // staging: wave v covers K key-rows [v*8,+8) and V d-rows [v*8,+8),
  // 1 gll16 each (8 rows x 8 chunk-slots), stored slot = chunk ^ (row & 7)
  const int srow = lane >> 3;                  // 0..7
  const int schk = (lane & 7) ^ srow;          // pre-swizzled global chunk
  const u16* gK = &Kp[((long)h * 4608 + qb0 + v * 8 + srow) * 64 + schk * 8];
  const u16* gV = &VTp[((long)h * 64 + v * 8 + srow) * 4608 + qb0 + schk * 8];
  const int lws = v * 512;                     // wave's LDS staging offset

  const int off0 = (quad ^ (c16 & 7)) * 8;     // chunk quad   at its slot
  const int off1 = ((4 + quad) ^ (c16 & 7)) * 8; // chunk 4+quad
  u16* const Pw = &Ps[v * 1024];
  const u16* rP = &Pw[c16 * 64];

  const int dbase = quad * 4 - s * 64 - 16 * w - c16; // delta = dbase + u*64 + tcol*16 + r

  f32x4 acc[4];
#pragma unroll
  for (int dt = 0; dt < 4; ++dt) acc[dt] = f32x4{0.f, 0.f, 0.f, 0.f};
  float rsum = 0.f;

  // stage one 64-key tile into (KsN, VsN), advancing the global cursors
  auto stage = [&](u16* KsN, u16* VsN) {
    gll16(gK, KsN + lws);
    gll16(gV, VsN + lws);
    gK += 64 * 64; gV += 64;
  };

  // consume one 64-key tile from (KsC, VsC); only if strip in band
  auto compute = [&](const u16* KsC, const u16* VsC, int u) {
    if ((u32)(u - s) >= 9u) return;    // strip0: u<9, strip1: 1<=u<10
    float p[4][4];   // [tcol][r], fully static-indexed
#pragma unroll
    for (int tcol = 0; tcol < 4; ++tcol) {
      const u16* kb = KsC + (tcol * 16 + c16) * 64;
      const bf16x8 bk0 = *(const bf16x8*)(kb + off0);
      const bf16x8 bk1 = *(const bf16x8*)(kb + off1);
      f32x4 sv = f32x4{0.f, 0.f, 0.f, 0.f};
      sv = MFMA16(bk0, aq0, sv);         // swapped: S^T[key][q]
      sv = MFMA16(bk1, aq1, sv);
#pragma unroll
      for (int r = 0; r < 4; ++r) {
        const int delta = dbase + u * 64 + tcol * 16 + r;
        const float pv = ((u32)delta < 512u) ? __expf(sv[r]) : 0.f;
        rsum += pv;
        p[tcol][r] = pv;
      }
    }
    // pack pairs -> bf16x2, store b32 at row q=c16, kc = tcol*16+quad*4+2hh
#pragma unroll
    for (int tcol = 0; tcol < 4; ++tcol)
#pragma unroll
      for (int hh = 0; hh < 2; ++hh) {
        u32 pk;
        asm("v_cvt_pk_bf16_f32 %0, %1, %2"
            : "=v"(pk) : "v"(p[tcol][2 * hh]), "v"(p[tcol][2 * hh + 1]));
        const int kc = tcol * 16 + quad * 4 + 2 * hh;
        *(u32*)(&Pw[c16 * 64 + (((kc >> 3) ^ (c16 & 7)) * 8) + (kc & 7)]) = pk;
      }
    const bf16x8 ap0 = *(const bf16x8*)(rP + off0);
    const bf16x8 ap1 = *(const bf16x8*)(rP + off1);
    __builtin_amdgcn_s_setprio(1);
#pragma unroll
    for (int dt = 0; dt < 4; ++dt) {
      const u16* vb = VsC + (dt * 16 + c16) * 64;
      const bf16x8 bv0 = *(const bf16x8*)(vb + off0);
      const bf16x8 bv1 = *(const bf16x8*)(vb + off1);
      acc[dt] = MFMA16(ap0, bv0, acc[dt]);
      acc[dt] = MFMA16(ap1, bv1, acc[dt]);
    }
    __builtin_amdgcn_s_setprio(0);
  };

  u16* const KsA = &Ks[0][0]; u16* const KsB = &Ks[1][0];
  u16* const VsA = &Vs[0][0]; u16* const VsB = &Vs[1][0];

  stage(KsA, VsA);                 // tile 0 -> A
  __syncthreads();
  for (int uu = 0; uu < 4; ++uu) {
    const int u = uu * 2;
    stage(KsB, VsB);               // tile u+1 -> B
    compute(KsA, VsA, u);
    __syncthreads();
    stage(KsA, VsA);               // tile u+2 -> A  (uu=3 stages tile 8)
    compute(KsB, VsB, u + 1);
    __syncthreads();
  }
  stage(KsB, VsB);                 // tile 9 -> B
  compute(KsA, VsA, 8);            // tile 8
  __syncthreads();
  compute(KsB, VsB, 9);            // tile 9 (strip1 only)

  // denom: rsum holds partial for q=c16 over this lane's quads/keys;
  // sum across the 4 quads, then every lane's rsum(q=c16) is complete.
  rsum += __shfl_xor(rsum, 16, 64);
  rsum += __shfl_xor(rsum, 32, 64);

  const int qp = qb0 + s * 64 + w * 16 + quad * 4;
#pragma unroll
  for (int r = 0; r < 4; ++r) {
    // output row q_local = quad*4 + r; its denom lives at lane (quad*4+r)
    const float dq = __shfl(rsum, quad * 4 + r, 64);
    const float inv = 1.f / dq;
#pragma unroll
    for (int dt = 0; dt < 4; ++dt)
      o[(long)(qp + r) * 1024 + h * 64 + dt * 16 + c16] = f2b(acc[dt][r] * inv);
  }
}

// ---------------------------------------------------------------------------
extern "C" void kernel_launch(void* const* d_in, const int* in_sizes, int n_in,
                              void* d_out, int out_size, void* d_ws, size_t ws_size,
                              hipStream_t stream)
{
  const float* x    = (const float*)d_in[0];   // (4096, 1024)
  const float* Wqkv = (const float*)d_in[1];   // (3072, 1024)
  const float* bqkv = (const float*)d_in[2];   // (3072,)
  const float* Wout = (const float*)d_in[3];   // (1024, 1024)
  const float* bout = (const float*)d_in[4];   // (1024,)
  float* out = (float*)d_out;                  // (4096, 1024)

  // ws layout (u16 elements); xb|wqkvb|woutb contiguous for cvt_all
  u16* xb    = (u16*)d_ws;                         // 4096*1024
  u16* wqkvb = xb    + (size_t)4096 * 1024;        // 3072*1024
  u16* woutb = wqkvb + (size_t)3072 * 1024;        // 1024*1024
  u16* Qb    = woutb + (size_t)1024 * 1024;        // 4096*1024
  u16* Kp    = Qb    + (size_t)4096 * 1024;        // 16*4608*64
  u16* VTp   = Kp    + (size_t)16 * 4608 * 64;     // 16*64*4608
  u16* o     = VTp   + (size_t)16 * 4608 * 64;     // 4096*1024

  // 1048576 convert chunks + 131072 pad-zero chunks
  cvt_all<<<(1048576 + 131072) / 256, 256, 0, stream>>>(x, Wqkv, Wout, xb, Kp, VTp);

  gemm_qkv<<<dim3(3072 / 128, 4096 / 128), 256, 0, stream>>>(
      xb, wqkvb, bqkv, Qb, Kp, VTp);
  swa_fused<<<512, 512, 0, stream>>>(Qb, Kp, VTp, o);
  gemm_out<<<1024, 256, 0, stream>>>(o, woutb, bout, out);
}

// Round 10
// 149.888 us; speedup vs baseline: 1.0254x; 1.0254x over previous
//
#include <hip/hip_runtime.h>

// SlidingWindowAttention: B=1, S=4096, D=1024, H=16, d=64, WIN=512 (256 back / 255 fwd)
// Inputs/outputs FP32 storage (values bf16-rounded by harness).
//
// Pipeline (4 dispatches) — best-verified configuration (R8, 150.6 us):
//   0) cvt_all   : x|Wqkv|Wout -> bf16 (contiguous ws) + zero Kp/VTp pad tiles
//   1) gemm_qkv  : 128x128 tile (m97 structure), BK=64, grid (24,32)=768 = 3/CU
//   2) swa_fused : 64 q/block, 4 waves, flat grid 1024 = 4 blocks/CU,
//                  XCD-locality swizzle; 64-key double-buffered rounds
//                  (9 tiles), swapped-QK^T (S^T) softmax: P lane-local in
//                  q=c16, cvt_pk P-store, scalar rsum + shfl reduce
//   3) gemm_out  : 64x64 tile @ 4 blocks/CU, XCD-contiguous remap,
//                  double-buffered LDS (one barrier/round)
//
// Negative results locked in (do NOT revisit):
//   - R18/R19: cooperative-launch dispatch fusion FAILS here (graph-capture
//     silently skips cooperative kernels; cross-XCD o-handoff races).
//   - R20: 128-q/8-wave swa blocks regress ~3 us (512-thread barrier
//     locksteps 8 waves; 2 blocks/CU loses scheduler independence).
//   - 64x128 gemm_out @ 2 blocks/CU regresses ~3 us (same mechanism).
//   - Explicit LDS dbuf in swa/gemm_out is neutral (4-block TLP already
//     hides staging); kept only where already present.

typedef __bf16 bf16x8 __attribute__((ext_vector_type(8)));
typedef float f32x4 __attribute__((ext_vector_type(4)));
typedef unsigned short u16;
typedef unsigned int u32;

#define MFMA16(a, b, c) __builtin_amdgcn_mfma_f32_16x16x32_bf16(a, b, c, 0, 0, 0)

__device__ __forceinline__ u16 f2b(float f) {   // RNE f32 -> bf16 bits
  union { float f; u32 u; } x; x.f = f;
  u32 r = x.u + 0x7fffu + ((x.u >> 16) & 1u);
  return (u16)(r >> 16);
}

union U8x16 { int4 v; u16 u[8]; };

// async 16B global -> LDS (dest = wave-uniform base + lane*16, HW-generated)
__device__ __forceinline__ void gll16(const u16* g, u16* l) {
  __builtin_amdgcn_global_load_lds(
      (const __attribute__((address_space(1))) u16*)g,
      (__attribute__((address_space(3))) u16*)l, 16, 0, 0);
}

// ---------------------------------------------------------------------------
// fp32 -> bf16 for all three inputs (chunks 0..1048575, contiguous dst) plus
// pad-zeroing of Kp (chunks +0..65535) and VTp (chunks +65536..131071).
// ---------------------------------------------------------------------------
__global__ void cvt_all(const float* __restrict__ x, const float* __restrict__ wqkv,
                        const float* __restrict__ wout, u16* __restrict__ dst,
                        u16* __restrict__ Kp, u16* __restrict__ VTp)
{
  const int i = blockIdx.x * blockDim.x + threadIdx.x;   // chunk index
  if (i < 1048576) {
    const float* src; int off;
    if (i < 524288)       { src = x;    off = i; }           // 4096*1024/8
    else if (i < 917504)  { src = wqkv; off = i - 524288; }  // +3072*1024/8
    else                  { src = wout; off = i - 917504; }  // +1024*1024/8
    const float4 a = ((const float4*)src)[off * 2];
    const float4 b = ((const float4*)src)[off * 2 + 1];
    U8x16 t;
    t.u[0] = f2b(a.x); t.u[1] = f2b(a.y); t.u[2] = f2b(a.z); t.u[3] = f2b(a.w);
    t.u[4] = f2b(b.x); t.u[5] = f2b(b.y); t.u[6] = f2b(b.z); t.u[7] = f2b(b.w);
    ((int4*)dst)[i] = t.v;
    return;
  }
  const int j = i - 1048576;
  const int4 z = {0, 0, 0, 0};
  if (j < 65536) {        // Kp pad rows: per h, rows [0,256) and [4352,4608)
    const int h = j >> 12, rem = j & 4095;
    const int row512 = rem >> 3, c8 = (rem & 7) * 8;
    const int row = (row512 < 256) ? row512 : (4096 + row512);
    *(int4*)(&Kp[((long)h * 4608 + row) * 64 + c8]) = z;
  } else {                // VTp pad cols: per h, keys [0,256) and [4352,4608)
    const int j2 = j - 65536;
    const int h = j2 >> 12, rem = j2 & 4095;
    const int d = rem >> 6, kc = rem & 63;
    const int key = (kc < 32) ? kc * 8 : (4096 + kc * 8);
    *(int4*)(&VTp[((long)h * 64 + d) * 4608 + key]) = z;
  }
}

// ---------------------------------------------------------------------------
// QKV GEMM: 128x128 tile (m97 structure), BK=64, grid (24, 32) = 768 blocks
// = 3/CU. LDS 32 KB shared pool. 4 waves x 64x64 quadrant, 32 MFMA/round.
// Epilogue: Q -> Qb * 0.125; K -> Kp direct scatter; V -> 32KB LDS re-tile.
// ---------------------------------------------------------------------------
__global__ __launch_bounds__(256, 3) void gemm_qkv(
    const u16* __restrict__ A, const u16* __restrict__ B,
    const float* __restrict__ bias,
    u16* __restrict__ Qb, u16* __restrict__ Kp, u16* __restrict__ VTp)
{
  __shared__ u16 smem[16384];    // 32 KB: As = smem[0..8191], Bs = smem[8192..]
  u16* const As = smem;          // 128 x 64
  u16* const Bs = smem + 8192;   // 128 x 64

  const int K = 1024;
  const int tid  = threadIdx.x;
  const int lane = tid & 63;
  const int wave = tid >> 6;
  const int quad = lane >> 4;
  const int c16  = lane & 15;
  const int wr   = wave >> 1;            // M half (64 rows)
  const int wc   = wave & 1;             // N half (64 cols)
  const long m0 = (long)blockIdx.y * 128;
  const long n0 = (long)blockIdx.x * 128;

  const int rowo   = lane >> 3;
  const int schunk = (lane & 7) ^ rowo;
  const u16* gA0 = &A[(m0 + wave * 32 + rowo) * K + schunk * 8];
  const u16* gA1 = gA0 + 8 * K;
  const u16* gA2 = gA0 + 16 * K;
  const u16* gA3 = gA0 + 24 * K;
  const u16* gB0 = &B[(n0 + wave * 32 + rowo) * K + schunk * 8];
  const u16* gB1 = gB0 + 8 * K;
  const u16* gB2 = gB0 + 16 * K;
  const u16* gB3 = gB0 + 24 * K;
  u16* const lA0 = &As[(wave * 32) * 64];
  u16* const lA1 = lA0 + 8 * 64;
  u16* const lA2 = lA0 + 16 * 64;
  u16* const lA3 = lA0 + 24 * 64;
  u16* const lB0 = &Bs[(wave * 32) * 64];
  u16* const lB1 = lB0 + 8 * 64;
  u16* const lB2 = lB0 + 16 * 64;
  u16* const lB3 = lB0 + 24 * 64;

  const int rsw  = c16 & 7;
  const int off0 = (quad ^ rsw) * 8;
  const int off1 = ((4 + quad) ^ rsw) * 8;
  const u16* rA[4]; const u16* rB[4];
#pragma unroll
  for (int i = 0; i < 4; ++i) rA[i] = &As[(wr * 64 + i * 16 + c16) * 64];
#pragma unroll
  for (int j = 0; j < 4; ++j) rB[j] = &Bs[(wc * 64 + j * 16 + c16) * 64];

  f32x4 acc[4][4];
#pragma unroll
  for (int i = 0; i < 4; ++i)
#pragma unroll
    for (int j = 0; j < 4; ++j)
      acc[i][j] = f32x4{0.f, 0.f, 0.f, 0.f};

  for (int k0 = 0; k0 < K; k0 += 64) {
    __syncthreads();
    gll16(gA0, lA0); gll16(gA1, lA1); gll16(gA2, lA2); gll16(gA3, lA3);
    gll16(gB0, lB0); gll16(gB1, lB1); gll16(gB2, lB2); gll16(gB3, lB3);
    gA0 += 64; gA1 += 64; gA2 += 64; gA3 += 64;
    gB0 += 64; gB1 += 64; gB2 += 64; gB3 += 64;
    __syncthreads();

#pragma unroll
    for (int h = 0; h < 2; ++h) {
      const int off = h ? off1 : off0;
      bf16x8 af[4], bfr[4];
#pragma unroll
      for (int i = 0; i < 4; ++i) af[i]  = *(const bf16x8*)(rA[i] + off);
#pragma unroll
      for (int j = 0; j < 4; ++j) bfr[j] = *(const bf16x8*)(rB[j] + off);
#pragma unroll
      for (int i = 0; i < 4; ++i)
#pragma unroll
        for (int j = 0; j < 4; ++j)
          acc[i][j] = MFMA16(af[i], bfr[j], acc[i][j]);
    }
  }

  const int region = (int)(n0 >> 10);      // 0=Q, 1=K, 2=V (block-uniform)
  if (region == 2) {
    // V: re-tile through LDS (transposed, 16-slot swizzled), then coalesced
    // 16B stores: 16 consecutive lanes cover one (h,d) row's 128 keys = 256 B.
    __syncthreads();                        // fragment reads of smem complete
    u16* const Ts = smem;                   // 128 cols x 128 keys (32 KB)
#pragma unroll
    for (int i = 0; i < 4; ++i)
#pragma unroll
      for (int j = 0; j < 4; ++j) {
        const int col = wc * 64 + j * 16 + c16;
        const float bv = bias[n0 + col];
#pragma unroll
        for (int r = 0; r < 4; ++r) {
          const int key  = wr * 64 + i * 16 + quad * 4 + r;   // block-local
          const int slot = (key >> 3) ^ (col & 15);
          Ts[col * 128 + slot * 8 + (key & 7)] = f2b(acc[i][j][r] + bv);
        }
      }
    __syncthreads();
    const int base_n1 = (int)(n0 - 2048);
#pragma unroll
    for (int k = 0; k < 8; ++k) {
      const int idx  = k * 256 + tid;
      const int col  = idx >> 4, kc = idx & 15;
      const int slot = kc ^ (col & 15);
      const int4 v = *(const int4*)(&Ts[col * 128 + slot * 8]);
      const int n1 = base_n1 + col;
      const int h = n1 >> 6, d = n1 & 63;
      *(int4*)(&VTp[((long)h * 64 + d) * 4608 + 256 + m0 + kc * 8]) = v;
    }
    return;
  }

#pragma unroll
  for (int i = 0; i < 4; ++i) {
    const long row0 = m0 + wr * 64 + i * 16 + quad * 4;
#pragma unroll
    for (int j = 0; j < 4; ++j) {
      const long col = n0 + wc * 64 + j * 16 + c16;
      const float bv = bias[col];
      if (region == 0) {
        // fold the 1/sqrt(d)=0.125 score scale into Q (exact pow2 scaling)
#pragma unroll
        for (int r = 0; r < 4; ++r)
          Qb[(row0 + r) * 1024 + col] = f2b((acc[i][j][r] + bv) * 0.125f);
      } else {
        const int n1 = (int)(col - 1024);
        const int h = n1 >> 6, d = n1 & 63;
#pragma unroll
        for (int r = 0; r < 4; ++r)
          Kp[((long)h * 4608 + row0 + r + 256) * 64 + d] = f2b(acc[i][j][r] + bv);
      }
    }
  }
}

// ---------------------------------------------------------------------------
// Output GEMM: 64x64 tile, BK=64, flat grid 1024 = 4 blocks/CU.
// XCD-contiguous remap: lb = (b&7)*128 + (b>>3), bijective on 1024.
// Double-buffered LDS; one barrier/round. 8 MFMA/round, 16 rounds. fp32 out.
// ---------------------------------------------------------------------------
__global__ __launch_bounds__(256, 4) void gemm_out(
    const u16* __restrict__ A, const u16* __restrict__ B,
    const float* __restrict__ bias, float* __restrict__ C)
{
  __shared__ u16 As[2][64 * 64];   // 16 KB
  __shared__ u16 Bs[2][64 * 64];   // 16 KB

  const int K = 1024, N = 1024;
  const int tid  = threadIdx.x;
  const int lane = tid & 63;
  const int wave = tid >> 6;
  const int quad = lane >> 4;
  const int c16  = lane & 15;
  const int wr   = wave >> 1;
  const int wc   = wave & 1;
  const int b    = blockIdx.x;
  const int lb   = (b & 7) * 128 + (b >> 3);   // XCD-contiguous (bijective)
  const long m0 = (long)(lb >> 4) * 64;
  const long n0 = (long)(lb & 15) * 64;

  const int rowo   = lane >> 3;
  const int schunk = (lane & 7) ^ rowo;
  const u16* gA0 = &A[(m0 + wave * 16 + rowo) * K + schunk * 8];
  const u16* gA1 = gA0 + 8 * K;
  const u16* gB0 = &B[(n0 + wave * 16 + rowo) * K + schunk * 8];
  const u16* gB1 = gB0 + 8 * K;
  const int lso = (wave * 16) * 64;            // wave's staging offset in a buf

  const int rsw  = c16 & 7;
  const int off0 = (quad ^ rsw) * 8;
  const int off1 = ((4 + quad) ^ rsw) * 8;
  const int ra0 = (wr * 32 + c16) * 64;        // fragment row offsets in a buf
  const int ra1 = (wr * 32 + 16 + c16) * 64;
  const int rb0 = (wc * 32 + c16) * 64;
  const int rb1 = (wc * 32 + 16 + c16) * 64;

  f32x4 acc[2][2];
#pragma unroll
  for (int i = 0; i < 2; ++i)
#pragma unroll
    for (int j = 0; j < 2; ++j)
      acc[i][j] = f32x4{0.f, 0.f, 0.f, 0.f};

  auto stage = [&](u16* Ab, u16* Bb) {
    gll16(gA0, Ab + lso); gll16(gA1, Ab + lso + 512);
    gll16(gB0, Bb + lso); gll16(gB1, Bb + lso + 512);
    gA0 += 64; gA1 += 64; gB0 += 64; gB1 += 64;
  };

  auto compute = [&](const u16* Ab, const u16* Bb) {
#pragma unroll
    for (int h = 0; h < 2; ++h) {
      const int off = h ? off1 : off0;
      bf16x8 af[2], bfr[2];
      af[0]  = *(const bf16x8*)(Ab + ra0 + off);
      af[1]  = *(const bf16x8*)(Ab + ra1 + off);
      bfr[0] = *(const bf16x8*)(Bb + rb0 + off);
      bfr[1] = *(const bf16x8*)(Bb + rb1 + off);
#pragma unroll
      for (int i = 0; i < 2; ++i)
#pragma unroll
        for (int j = 0; j < 2; ++j)
          acc[i][j] = MFMA16(af[i], bfr[j], acc[i][j]);
    }
  };

  u16* const A0 = &As[0][0]; u16* const A1 = &As[1][0];
  u16* const B0 = &Bs[0][0]; u16* const B1 = &Bs[1][0];

  stage(A0, B0);                   // t0 -> buf0
  __syncthreads();
  for (int uu = 0; uu < 7; ++uu) { // rounds t=2uu, 2uu+1  (t=0..13)
    stage(A1, B1);                 // t+1 -> buf1
    compute(A0, B0);               // t
    __syncthreads();
    stage(A0, B0);                 // t+2 -> buf0
    compute(A1, B1);               // t+1
    __syncthreads();
  }
  stage(A1, B1);                   // t15 -> buf1
  compute(A0, B0);                 // t14
  __syncthreads();
  compute(A1, B1);                 // t15

#pragma unroll
  for (int i = 0; i < 2; ++i) {
    const long row0 = m0 + wr * 32 + i * 16 + quad * 4;
#pragma unroll
    for (int j = 0; j < 2; ++j) {
      const long col = n0 + wc * 32 + j * 16 + c16;
      const float bv = bias[col];
#pragma unroll
      for (int r = 0; r < 4; ++r)
        C[(row0 + r) * N + col] = acc[i][j][r] + bv;
    }
  }
}

// ---------------------------------------------------------------------------
// Sliding-window flash attention. Flat grid 1024 blocks, 256 thr = 4 waves,
// LDS 40 KB -> 4 blocks/CU. XCD-locality swizzle: xcd = b & 7.
//
// 64-key double-buffered rounds; 9 tiles cover padded keys [qb0, qb0+576).
// Swapped-QK^T softmax (S^T via MFMA16(bk,aq)): lane holds
// S[key = tcol*16 + quad*4 + r][q = c16]; P-store = 8 cvt_pk + 8 ds_write_b32;
// rsum scalar/lane + 2 shfl_xor; PV read path unchanged.
// ---------------------------------------------------------------------------
__global__ __launch_bounds__(256, 4) void swa_fused(
    const u16* __restrict__ Qb, const u16* __restrict__ Kp,
    const u16* __restrict__ VTp, u16* __restrict__ o)
{
  __shared__ u16 Ks[2][64 * 64];    // (key, d) dbuf   16 KB
  __shared__ u16 Vs[2][64 * 64];    // (d, key) dbuf   16 KB
  __shared__ u16 Ps[4 * 16 * 64];   // per-wave (q,key) 8 KB

  const int tid  = threadIdx.x;
  const int lane = tid & 63;
  const int w    = tid >> 6;
  const int quad = lane >> 4;
  const int c16  = lane & 15;

  // XCD-locality remap: b -> (h, qb0)
  const int b    = blockIdx.x;
  const int xcd  = b & 7;
  const int idx  = b >> 3;               // 0..127, ascending in launch order
  const int h    = xcd * 2 + (idx >> 6); // heads {2x, 2x+1}
  const int qb0  = (idx & 63) * 64;      // qb ascending within XCD

  const long qrow = qb0 + w * 16 + c16;
  const bf16x8 aq0 = *(const bf16x8*)(&Qb[qrow * 1024 + h * 64 + quad * 8]);
  const bf16x8 aq1 = *(const bf16x8*)(&Qb[qrow * 1024 + h * 64 + 32 + quad * 8]);

  // staging: wave w covers K key-rows [w*16,+16) and V d-rows [w*16,+16),
  // 2 gll16 each (8 rows x 8 chunk-slots), stored slot = chunk ^ (row & 7)
  const int srow = lane >> 3;                  // 0..7
  const int schk = (lane & 7) ^ srow;          // pre-swizzled global chunk
  const u16* gK  = &Kp[((long)h * 4608 + qb0 + w * 16 + srow) * 64 + schk * 8];
  const u16* gV0 = &VTp[((long)h * 64 + w * 16 + srow) * 4608 + qb0 + schk * 8];
  const u16* gV1 = gV0 + 8 * 4608;
  const int lws  = w * 1024;                   // wave's LDS staging offset

  const int off0 = (quad ^ (c16 & 7)) * 8;     // chunk quad   at its slot
  const int off1 = ((4 + quad) ^ (c16 & 7)) * 8; // chunk 4+quad
  u16* const Pw = &Ps[w * 1024];
  const u16* rP = &Pw[c16 * 64];

  const int dbase = quad * 4 - 16 * w - c16;   // delta = dbase + u*64 + tcol*16 + r

  f32x4 acc[4];
#pragma unroll
  for (int dt = 0; dt < 4; ++dt) acc[dt] = f32x4{0.f, 0.f, 0.f, 0.f};
  float rsum = 0.f;

  // stage one 64-key tile into (KsN, VsN), advancing the global cursors
  auto stage = [&](u16* KsN, u16* VsN) {
    gll16(gK,           KsN + lws);
    gll16(gK + 8 * 64,  KsN + lws + 512);
    gll16(gV0,          VsN + lws);
    gll16(gV1,          VsN + lws + 512);
    gK += 64 * 64; gV0 += 64; gV1 += 64;
  };

  // consume one 64-key tile from (KsC, VsC)
  auto compute = [&](const u16* KsC, const u16* VsC, int u) {
    float p[4][4];   // [tcol][r], fully static-indexed
#pragma unroll
    for (int tcol = 0; tcol < 4; ++tcol) {
      const u16* kb = KsC + (tcol * 16 + c16) * 64;
      const bf16x8 bk0 = *(const bf16x8*)(kb + off0);
      const bf16x8 bk1 = *(const bf16x8*)(kb + off1);
      f32x4 s = f32x4{0.f, 0.f, 0.f, 0.f};
      s = MFMA16(bk0, aq0, s);           // swapped: S^T[key][q]
      s = MFMA16(bk1, aq1, s);
#pragma unroll
      for (int r = 0; r < 4; ++r) {
        const int delta = dbase + u * 64 + tcol * 16 + r;
        const float pv = ((u32)delta < 512u) ? __expf(s[r]) : 0.f;
        rsum += pv;
        p[tcol][r] = pv;
      }
    }
    // pack pairs -> bf16x2, store b32 at row q=c16, kc = tcol*16+quad*4+2hh
#pragma unroll
    for (int tcol = 0; tcol < 4; ++tcol)
#pragma unroll
      for (int hh = 0; hh < 2; ++hh) {
        u32 pk;
        asm("v_cvt_pk_bf16_f32 %0, %1, %2"
            : "=v"(pk) : "v"(p[tcol][2 * hh]), "v"(p[tcol][2 * hh + 1]));
        const int kc = tcol * 16 + quad * 4 + 2 * hh;
        *(u32*)(&Pw[c16 * 64 + (((kc >> 3) ^ (c16 & 7)) * 8) + (kc & 7)]) = pk;
      }
    const bf16x8 ap0 = *(const bf16x8*)(rP + off0);
    const bf16x8 ap1 = *(const bf16x8*)(rP + off1);
    __builtin_amdgcn_s_setprio(1);
#pragma unroll
    for (int dt = 0; dt < 4; ++dt) {
      const u16* vb = VsC + (dt * 16 + c16) * 64;
      const bf16x8 bv0 = *(const bf16x8*)(vb + off0);
      const bf16x8 bv1 = *(const bf16x8*)(vb + off1);
      acc[dt] = MFMA16(ap0, bv0, acc[dt]);
      acc[dt] = MFMA16(ap1, bv1, acc[dt]);
    }
    __builtin_amdgcn_s_setprio(0);
  };

  u16* const KsA = &Ks[0][0]; u16* const KsB = &Ks[1][0];
  u16* const VsA = &Vs[0][0]; u16* const VsB = &Vs[1][0];

  stage(KsA, VsA);                 // tile 0 -> A
  __syncthreads();
  for (int uu = 0; uu < 4; ++uu) {
    const int u = uu * 2;
    stage(KsB, VsB);               // tile u+1 -> B
    compute(KsA, VsA, u);
    __syncthreads();
    stage(KsA, VsA);               // tile u+2 -> A  (uu=3 stages tile 8)
    compute(KsB, VsB, u + 1);
    __syncthreads();
  }
  compute(KsA, VsA, 8);            // tile 8, no further staging

  // denom: rsum holds partial for q=c16 over this lane's quads/keys;
  // sum across the 4 quads, then every lane's rsum(q=c16) is complete.
  rsum += __shfl_xor(rsum, 16, 64);
  rsum += __shfl_xor(rsum, 32, 64);

  const int qp = qb0 + w * 16 + quad * 4;
#pragma unroll
  for (int r = 0; r < 4; ++r) {
    // output row q_local = quad*4 + r; its denom lives at lane (quad*4+r)
    const float dq = __shfl(rsum, quad * 4 + r, 64);
    const float inv = 1.f / dq;
#pragma unroll
    for (int dt = 0; dt < 4; ++dt)
      o[(long)(qp + r) * 1024 + h * 64 + dt * 16 + c16] = f2b(acc[dt][r] * inv);
  }
}

// ---------------------------------------------------------------------------
extern "C" void kernel_launch(void* const* d_in, const int* in_sizes, int n_in,
                              void* d_out, int out_size, void* d_ws, size_t ws_size,
                              hipStream_t stream)
{
  const float* x    = (const float*)d_in[0];   // (4096, 1024)
  const float* Wqkv = (const float*)d_in[1];   // (3072, 1024)
  const float* bqkv = (const float*)d_in[2];   // (3072,)
  const float* Wout = (const float*)d_in[3];   // (1024, 1024)
  const float* bout = (const float*)d_in[4];   // (1024,)
  float* out = (float*)d_out;                  // (4096, 1024)

  // ws layout (u16 elements); xb|wqkvb|woutb contiguous for cvt_all
  u16* xb    = (u16*)d_ws;                         // 4096*1024
  u16* wqkvb = xb    + (size_t)4096 * 1024;        // 3072*1024
  u16* woutb = wqkvb + (size_t)3072 * 1024;        // 1024*1024
  u16* Qb    = woutb + (size_t)1024 * 1024;        // 4096*1024
  u16* Kp    = Qb    + (size_t)4096 * 1024;        // 16*4608*64
  u16* VTp   = Kp    + (size_t)16 * 4608 * 64;     // 16*64*4608
  u16* o     = VTp   + (size_t)16 * 4608 * 64;     // 4096*1024

  // 1048576 convert chunks + 131072 pad-zero chunks
  cvt_all<<<(1048576 + 131072) / 256, 256, 0, stream>>>(x, Wqkv, Wout, xb, Kp, VTp);

  gemm_qkv<<<dim3(3072 / 128, 4096 / 128), 256, 0, stream>>>(
      xb, wqkvb, bqkv, Qb, Kp, VTp);
  swa_fused<<<1024, 256, 0, stream>>>(Qb, Kp, VTp, o);
  gemm_out<<<1024, 256, 0, stream>>>(o, woutb, bout, out);
}